// Round 7
// baseline (338.955 us; speedup 1.0000x reference)
//
#include <hip/hip_runtime.h>
#include <math.h>

// GraphAttn: B=16, N=2048, feat = C*F = 64.
//  xf = W @ x + bias   (per batch, 2048x2048 * 2048x64)
//  s1[b,o] = xf[b,o,:] . att1
//  s2[b,o] = W @ (n . att2) + bias*sum(att2)   [conv linearity]
//  a = leaky_relu(s1[j]+s2[i]); softmax over i; out = a^T-weighted sums of xf
//  Separable softmax via per-batch sort + prefix/suffix scans (round 3, proven).
//
// R7 == R4 resubmit (R4, R5, R6 never ran: GPU acquisition timeouts).
// k1_conv (142us fp32 VALU GEMM) -> split-bf16 MFMA GEMM:
//     W@x = Wh@xh + Wh@xl + Wl@xh  (RNE hi/lo split, err ~1e-5)
//     + one-time convert kernels. Fallback to fp32 path if ws_size too small.
//
// ws layout: [smalls 1.44MB][PA/PB 16MB == overlay Wh/Wl][xh/xl 8MB]
//   fallback uses only smalls+PA/PB = 18.2MB (proven in R3).

#define BB 16
#define NN 2048
#define FEAT 64
#define BM 64
#define BK 32
#define NCH 16
#define CHL 128

typedef __attribute__((ext_vector_type(8))) short short8v;   // 8 bf16
typedef __attribute__((ext_vector_type(8))) ushort ushort8v;
typedef __attribute__((ext_vector_type(4))) float f32x4;

__device__ __forceinline__ float lrelu(float t) {
    return fmaxf(t, 0.2f * t);
}

__device__ __forceinline__ ushort bf16_rne(float f) {
    unsigned u = __float_as_uint(f);
    unsigned r = u + 0x7FFF + ((u >> 16) & 1);
    return (ushort)(r >> 16);
}
__device__ __forceinline__ float bf16_to_f(ushort h) {
    return __uint_as_float(((unsigned)h) << 16);
}

// ---------------------------------------------------------------- k_cvtW
// W fp32 -> Wh, Wl bf16 (hi/lo split)
__global__ __launch_bounds__(256) void k_cvtW(
        const float* __restrict__ W, ushort* __restrict__ Wh,
        ushort* __restrict__ Wl) {
    int idx = (blockIdx.x * 256 + threadIdx.x) * 4;
    float4 w = *(const float4*)(W + idx);
    ushort h0 = bf16_rne(w.x), h1 = bf16_rne(w.y),
           h2 = bf16_rne(w.z), h3 = bf16_rne(w.w);
    ushort l0 = bf16_rne(w.x - bf16_to_f(h0)), l1 = bf16_rne(w.y - bf16_to_f(h1)),
           l2 = bf16_rne(w.z - bf16_to_f(h2)), l3 = bf16_rne(w.w - bf16_to_f(h3));
    *(ushort4*)(Wh + idx) = make_ushort4(h0, h1, h2, h3);
    *(ushort4*)(Wl + idx) = make_ushort4(l0, l1, l2, l3);
}

// ---------------------------------------------------------------- k_cvtX
// x [b][k][f] fp32 -> xh,xl [b][f][k] bf16 (transposed for B-operand reads)
__global__ __launch_bounds__(256) void k_cvtX(
        const float* __restrict__ x, ushort* __restrict__ xh,
        ushort* __restrict__ xl) {
    __shared__ float tile[64][65];
    const int k0 = blockIdx.x * 64, b = blockIdx.y, t = threadIdx.x;
#pragma unroll
    for (int i = 0; i < 4; ++i) {
        int row = (t >> 4) + i * 16, c4 = (t & 15) * 4;
        *(float4*)&tile[row][c4] =
            *(const float4*)(x + ((size_t)b * NN + k0 + row) * FEAT + c4);
    }
    __syncthreads();
    const int f = t >> 2, kg = t & 3;
    ushort hi[16], lo[16];
#pragma unroll
    for (int e = 0; e < 16; ++e) {
        float v = tile[kg * 16 + e][f];
        ushort h = bf16_rne(v);
        hi[e] = h;
        lo[e] = bf16_rne(v - bf16_to_f(h));
    }
    size_t base = ((size_t)b * FEAT + f) * NN + k0 + kg * 16;
#pragma unroll
    for (int q = 0; q < 2; ++q) {
        ushort8v vh, vl;
#pragma unroll
        for (int e = 0; e < 8; ++e) { vh[e] = hi[q * 8 + e]; vl[e] = lo[q * 8 + e]; }
        *(ushort8v*)(xh + base + q * 8) = vh;
        *(ushort8v*)(xl + base + q * 8) = vl;
    }
}

// ---------------------------------------------------------------- k1_mfma
// xf[b] = W @ x[b] + bias via 3-term split-bf16 MFMA.
// Block: 128 rows x 64 cols, one batch; 4 waves, wave = 32 rows x 64 cols
// (2x4 tiles of 16x16). BK=64. LDS tiles XOR-swizzled (byte ^= (row&7)<<4).
__global__ __launch_bounds__(256) void k1_mfma(
        const ushort* __restrict__ Wh, const ushort* __restrict__ Wl,
        const ushort* __restrict__ xh, const ushort* __restrict__ xl,
        const float* __restrict__ bias, float* __restrict__ xf) {
    __shared__ __align__(16) char lds[49152];   // Wh 16K | Wl 16K | Xh 8K | Xl 8K
    const int o0 = blockIdx.x * 128;
    const int b  = blockIdx.y;
    const int t  = threadIdx.x;
    const int wave = t >> 6, lane = t & 63;
    f32x4 acc[2][4] = {};
    uint4 stg[12];

    auto load_tile = [&](int k0) {
#pragma unroll
        for (int i = 0; i < 4; ++i) {
            int G = t + i * 256, row = G >> 3, gc = G & 7;
            size_t gsrc = (size_t)(o0 + row) * NN + k0 + gc * 8;
            stg[i]     = *(const uint4*)(Wh + gsrc);
            stg[4 + i] = *(const uint4*)(Wl + gsrc);
        }
#pragma unroll
        for (int i = 0; i < 2; ++i) {
            int G = t + i * 256, f = G >> 3, gc = G & 7;
            size_t gsrc = ((size_t)b * FEAT + f) * NN + k0 + gc * 8;
            stg[8 + i]  = *(const uint4*)(xh + gsrc);
            stg[10 + i] = *(const uint4*)(xl + gsrc);
        }
    };
    auto write_tile = [&]() {
#pragma unroll
        for (int i = 0; i < 4; ++i) {
            int G = t + i * 256, row = G >> 3, gc = G & 7;
            int off = (row * 128 + gc * 16) ^ ((row & 7) << 4);
            *(uint4*)(lds + off)         = stg[i];
            *(uint4*)(lds + 16384 + off) = stg[4 + i];
        }
#pragma unroll
        for (int i = 0; i < 2; ++i) {
            int G = t + i * 256, f = G >> 3, gc = G & 7;
            int off = (f * 128 + gc * 16) ^ ((f & 7) << 4);
            *(uint4*)(lds + 32768 + off) = stg[8 + i];
            *(uint4*)(lds + 40960 + off) = stg[10 + i];
        }
    };

    load_tile(0);
    for (int k0 = 0; k0 < NN; k0 += 64) {
        __syncthreads();                // previous compute done; LDS free
        write_tile();
        if (k0 + 64 < NN) load_tile(k0 + 64);   // prefetch next (hides HBM/L2)
        __syncthreads();
#pragma unroll
        for (int s = 0; s < 2; ++s) {   // two 16x16x32 k-subtiles of BK=64
            short8v Ah[2], Al[2], Bh[4], Bl[4];
#pragma unroll
            for (int rt = 0; rt < 2; ++rt) {
                int row = wave * 32 + rt * 16 + (lane & 15);
                int off = (row * 128 + s * 64 + ((lane >> 4) & 3) * 16)
                          ^ ((row & 7) << 4);
                Ah[rt] = *(const short8v*)(lds + off);
                Al[rt] = *(const short8v*)(lds + 16384 + off);
            }
#pragma unroll
            for (int ct = 0; ct < 4; ++ct) {
                int f = ct * 16 + (lane & 15);
                int off = (f * 128 + s * 64 + ((lane >> 4) & 3) * 16)
                          ^ ((f & 7) << 4);
                Bh[ct] = *(const short8v*)(lds + 32768 + off);
                Bl[ct] = *(const short8v*)(lds + 40960 + off);
            }
#pragma unroll
            for (int rt = 0; rt < 2; ++rt)
#pragma unroll
                for (int ct = 0; ct < 4; ++ct) {
                    acc[rt][ct] = __builtin_amdgcn_mfma_f32_16x16x32_bf16(
                        Ah[rt], Bh[ct], acc[rt][ct], 0, 0, 0);
                    acc[rt][ct] = __builtin_amdgcn_mfma_f32_16x16x32_bf16(
                        Ah[rt], Bl[ct], acc[rt][ct], 0, 0, 0);
                    acc[rt][ct] = __builtin_amdgcn_mfma_f32_16x16x32_bf16(
                        Al[rt], Bh[ct], acc[rt][ct], 0, 0, 0);
                }
        }
    }
    // epilogue: C/D layout col=lane&15, row=(lane>>4)*4+r   [m89/m91]
#pragma unroll
    for (int rt = 0; rt < 2; ++rt)
#pragma unroll
        for (int ct = 0; ct < 4; ++ct)
#pragma unroll
            for (int r = 0; r < 4; ++r) {
                int o = o0 + wave * 32 + rt * 16 + ((lane >> 4) & 3) * 4 + r;
                int f = ct * 16 + (lane & 15);
                xf[((size_t)b * NN + o) * FEAT + f] = acc[rt][ct][r] + bias[o];
            }
}

// ---------------------------------------------------------------- k1_conv (fallback, R3-proven)
__global__ __launch_bounds__(256) void k1_conv(
        const float* __restrict__ x, const float* __restrict__ W,
        const float* __restrict__ bias, float* __restrict__ xf) {
    __shared__ float Ws[BK][BM + 4];
    __shared__ float Xs[BK][FEAT];
    const int o0 = blockIdx.x * BM;
    const int b  = blockIdx.y;
    const int t  = threadIdx.x;
    const int ty = t >> 4, tx = t & 15;
    float acc[4][4] = {};
    for (int k0 = 0; k0 < NN; k0 += BK) {
#pragma unroll
        for (int r = 0; r < 2; ++r) {
            int v = t + r * 256;
            int m = v >> 3, k = (v & 7) * 4;
            float4 w4 = *(const float4*)(W + (size_t)(o0 + m) * NN + k0 + k);
            Ws[k + 0][m] = w4.x; Ws[k + 1][m] = w4.y;
            Ws[k + 2][m] = w4.z; Ws[k + 3][m] = w4.w;
        }
#pragma unroll
        for (int r = 0; r < 2; ++r) {
            int v = t + r * 256;
            int k = v >> 4, hw = (v & 15) * 4;
            *(float4*)&Xs[k][hw] =
                *(const float4*)(x + ((size_t)b * NN + k0 + k) * FEAT + hw);
        }
        __syncthreads();
#pragma unroll
        for (int kk = 0; kk < BK; ++kk) {
            float a[4], c[4];
            *(float4*)a = *(const float4*)&Ws[kk][ty * 4];
            *(float4*)c = *(const float4*)&Xs[kk][tx * 4];
#pragma unroll
            for (int ii = 0; ii < 4; ++ii)
#pragma unroll
                for (int ff = 0; ff < 4; ++ff)
                    acc[ii][ff] += a[ii] * c[ff];
        }
        __syncthreads();
    }
#pragma unroll
    for (int ii = 0; ii < 4; ++ii) {
        int o = o0 + ty * 4 + ii;
        float bv = bias[o];
        float4 r = make_float4(acc[ii][0] + bv, acc[ii][1] + bv,
                               acc[ii][2] + bv, acc[ii][3] + bv);
        *(float4*)(xf + ((size_t)b * NN + o) * FEAT + tx * 4) = r;
    }
}

// ---------------------------------------------------------------- k0: ntilde
__global__ __launch_bounds__(256) void k0_ntilde(
        const float* __restrict__ n, const float* __restrict__ att2,
        float* __restrict__ nt) {
    int t = blockIdx.x * 256 + threadIdx.x;
    int b = t >> 11, i = t & (NN - 1);
    const float4* row = (const float4*)(n + ((size_t)b * NN + i) * FEAT);
    const float4* a2  = (const float4*)att2;
    float s = 0.f;
#pragma unroll
    for (int q = 0; q < 16; ++q) {
        float4 v = row[q], w = a2[q];
        s += v.x * w.x + v.y * w.y + v.z * w.z + v.w * w.w;
    }
    nt[i * BB + b] = s;
}

// ---------------------------------------------------------------- k2: s2
__global__ __launch_bounds__(256) void k2_s2(
        const float* __restrict__ W, const float* __restrict__ nt,
        const float* __restrict__ bias, const float* __restrict__ att2,
        float* __restrict__ s2) {
    int t = blockIdx.x * 256 + threadIdx.x;
    int o = t >> 4, b = t & 15;
    float acc = 0.f;
    for (int i = 0; i < NN; i += 4) {
        float4 w4 = *(const float4*)(W + (size_t)o * NN + i);
        acc += w4.x * nt[(i + 0) * BB + b] + w4.y * nt[(i + 1) * BB + b]
             + w4.z * nt[(i + 2) * BB + b] + w4.w * nt[(i + 3) * BB + b];
    }
    float A2 = 0.f;
#pragma unroll
    for (int q = 0; q < FEAT; ++q) A2 += att2[q];
    s2[(size_t)b * NN + o] = acc + bias[o] * A2;
}

// ---------------------------------------------------------------- k2b: s1
__global__ __launch_bounds__(256) void k2b_s1(
        const float* __restrict__ xf, const float* __restrict__ att1,
        float* __restrict__ s1) {
    int t = blockIdx.x * 256 + threadIdx.x;
    const float4* row = (const float4*)(xf + (size_t)t * FEAT);
    const float4* a1  = (const float4*)att1;
    float s = 0.f;
#pragma unroll
    for (int q = 0; q < 16; ++q) {
        float4 v = row[q], w = a1[q];
        s += v.x * w.x + v.y * w.y + v.z * w.z + v.w * w.w;
    }
    s1[t] = s;
}

// ---------------------------------------------------------------- sort+scan
__device__ __forceinline__ void scan2048(float* buf, int t) {
    for (int off = 1; off < 2048; off <<= 1) {
        int i0 = t, i1 = t + 1024;
        float x0 = (i0 >= off) ? buf[i0 - off] : 0.f;
        float c0 = buf[i0];
        float x1 = (i1 >= off) ? buf[i1 - off] : 0.f;
        float c1 = buf[i1];
        __syncthreads();
        buf[i0] = c0 + x0;
        buf[i1] = c1 + x1;
        __syncthreads();
    }
}

__global__ __launch_bounds__(1024) void ksort(
        const float* __restrict__ s1, const float* __restrict__ s2,
        float* __restrict__ s1s, int* __restrict__ p1,
        float* __restrict__ s2s, float* __restrict__ E1suf,
        float* __restrict__ E2) {
    __shared__ float key[2048];
    __shared__ int   val[2048];
    __shared__ float buf[2048];
    const int b = blockIdx.y, arr = blockIdx.x, t = threadIdx.x;
    const float* src = (arr == 0 ? s1 : s2) + (size_t)b * NN;
    key[t] = src[t]; key[t + 1024] = src[t + 1024];
    val[t] = t;      val[t + 1024] = t + 1024;
    __syncthreads();
    for (int k = 2; k <= 2048; k <<= 1) {
        for (int j = k >> 1; j > 0; j >>= 1) {
#pragma unroll
            for (int r = 0; r < 2; ++r) {
                int i = r * 1024 + t;
                int l = i ^ j;
                if (l > i) {
                    bool up = ((i & k) == 0);
                    float ki = key[i], kl = key[l];
                    if (up ? (ki > kl) : (ki < kl)) {
                        key[i] = kl; key[l] = ki;
                        int vi = val[i]; val[i] = val[l]; val[l] = vi;
                    }
                }
            }
            __syncthreads();
        }
    }
    const size_t base = (size_t)b * NN;
    if (arr == 0) {
        s1s[base + t] = key[t]; s1s[base + t + 1024] = key[t + 1024];
        p1[base + t]  = val[t]; p1[base + t + 1024]  = val[t + 1024];
    } else {
        s2s[base + t] = key[t]; s2s[base + t + 1024] = key[t + 1024];
        buf[t] = __expf(0.2f * key[t]);
        buf[t + 1024] = __expf(0.2f * key[t + 1024]);
        __syncthreads();
        scan2048(buf, t);
        E2[base + t] = buf[t]; E2[base + t + 1024] = buf[t + 1024];
        __syncthreads();
        buf[t] = __expf(key[2047 - t]);
        buf[t + 1024] = __expf(key[2047 - (t + 1024)]);
        __syncthreads();
        scan2048(buf, t);
        E1suf[base + 2047 - t] = buf[t];
        E1suf[base + 2047 - (t + 1024)] = buf[t + 1024];
    }
}

// ---------------------------------------------------------------- k_ab
__global__ __launch_bounds__(256) void k_ab(
        const float* __restrict__ s1s, const float* __restrict__ s2s,
        const float* __restrict__ E1suf, const float* __restrict__ E2,
        float* __restrict__ as, float* __restrict__ bs) {
    int idx = blockIdx.x * 256 + threadIdx.x;
    int b = idx >> 11;
    const size_t base = (size_t)b * NN;
    float s1v = s1s[idx];
    float thr = -s1v;
    const float* S2 = s2s + base;
    int lo = 0, hi = NN;
    while (lo < hi) { int mid = (lo + hi) >> 1; if (S2[mid] < thr) lo = mid + 1; else hi = mid; }
    float e1 = (lo < NN) ? E1suf[base + lo] : 0.f;
    float e2 = (lo > 0)  ? E2[base + lo - 1] : 0.f;
    float ea = __expf(s1v), eb = __expf(0.2f * s1v);
    float zi = 1.0f / (ea * e1 + eb * e2);
    as[idx] = ea * zi;
    bs[idx] = eb * zi;
}

// ---------------------------------------------------------------- scans
__global__ __launch_bounds__(64) void kscanA(
        const int* __restrict__ p1, const float* __restrict__ as,
        const float* __restrict__ bs, const float* __restrict__ xf,
        float* __restrict__ CTA, float* __restrict__ CTB) {
    const int b = blockIdx.y, c = blockIdx.x, f = threadIdx.x;
    const size_t base = (size_t)b * NN;
    float sA = 0.f, sB = 0.f;
#pragma unroll 8
    for (int r = 0; r < CHL; ++r) {
        int t = c * CHL + r;
        int j = p1[base + t];
        float xv = xf[(base + j) * FEAT + f];
        sA += as[base + t] * xv;
        sB += bs[base + t] * xv;
    }
    CTA[((size_t)b * NCH + c) * FEAT + f] = sA;
    CTB[((size_t)b * NCH + c) * FEAT + f] = sB;
}

__global__ __launch_bounds__(64) void kscanB(
        const int* __restrict__ p1, const float* __restrict__ as,
        const float* __restrict__ bs, const float* __restrict__ xf,
        const float* __restrict__ CTA, const float* __restrict__ CTB,
        float* __restrict__ PA, float* __restrict__ PB) {
    const int b = blockIdx.y, c = blockIdx.x, f = threadIdx.x;
    const size_t base = (size_t)b * NN;
    float offA = 0.f, offB = 0.f;
    for (int cc = 0; cc < NCH; ++cc) {
        float av = CTA[((size_t)b * NCH + cc) * FEAT + f];
        float bv = CTB[((size_t)b * NCH + cc) * FEAT + f];
        if (cc > c) offA += av;
        if (cc < c) offB += bv;
    }
    float run = offB;
#pragma unroll 4
    for (int r = 0; r < CHL; ++r) {
        int t = c * CHL + r;
        int j = p1[base + t];
        float xv = xf[(base + j) * FEAT + f];
        run += bs[base + t] * xv;
        PB[(base + t) * FEAT + f] = run;
    }
    run = offA;
#pragma unroll 4
    for (int r = CHL - 1; r >= 0; --r) {
        int t = c * CHL + r;
        int j = p1[base + t];
        float xv = xf[(base + j) * FEAT + f];
        run += as[base + t] * xv;
        PA[(base + t) * FEAT + f] = run;
    }
}

// ---------------------------------------------------------------- k4
__global__ __launch_bounds__(256) void k4_sep(
        const float* __restrict__ s2, const float* __restrict__ s1s,
        const float* __restrict__ PA, const float* __restrict__ PB,
        float* __restrict__ out) {
    const int b = blockIdx.y;
    const int i = blockIdx.x * 16 + (threadIdx.x >> 4);
    const int fg = threadIdx.x & 15;
    const size_t base = (size_t)b * NN;
    float s2v = s2[base + i];
    float thr = -s2v;
    const float* S1 = s1s + base;
    int lo = 0, hi = NN;
    while (lo < hi) { int mid = (lo + hi) >> 1; if (S1[mid] < thr) lo = mid + 1; else hi = mid; }
    float eA = __expf(s2v), eB = __expf(0.2f * s2v);
    float4 pa = make_float4(0.f, 0.f, 0.f, 0.f);
    float4 pb = make_float4(0.f, 0.f, 0.f, 0.f);
    if (lo < NN) pa = *(const float4*)(PA + (base + lo) * FEAT + fg * 4);
    if (lo > 0)  pb = *(const float4*)(PB + (base + lo - 1) * FEAT + fg * 4);
    float4 o;
    o.x = eA * pa.x + eB * pb.x;
    o.y = eA * pa.y + eB * pb.y;
    o.z = eA * pa.z + eB * pb.z;
    o.w = eA * pa.w + eB * pb.w;
    *(float4*)(out + (base + i) * FEAT + fg * 4) = o;
}

extern "C" void kernel_launch(void* const* d_in, const int* in_sizes, int n_in,
                              void* d_out, int out_size, void* d_ws, size_t ws_size,
                              hipStream_t stream) {
    const float* x      = (const float*)d_in[0];
    const float* n      = (const float*)d_in[1];
    const float* conv_w = (const float*)d_in[2];
    const float* conv_b = (const float*)d_in[3];
    const float* att1   = (const float*)d_in[4];
    const float* att2   = (const float*)d_in[5];
    float* outp = (float*)d_out;
    float* xf = outp;   // xf aliases d_out (k4_sep overwrites all of it)

    // ---- ws layout: smalls | PA/PB (overlay Wh/Wl) | xh/xl
    float* ws    = (float*)d_ws;
    float* s1    = ws;
    float* s2    = s1    + (size_t)BB * NN;
    float* nt    = s2    + (size_t)BB * NN;
    float* s1s   = nt    + (size_t)BB * NN;
    int*   p1    = (int*)(s1s + (size_t)BB * NN);
    float* s2s   = (float*)p1 + (size_t)BB * NN;
    float* E1suf = s2s   + (size_t)BB * NN;
    float* E2    = E1suf + (size_t)BB * NN;
    float* as    = E2    + (size_t)BB * NN;
    float* bs    = as    + (size_t)BB * NN;
    float* CTA   = bs    + (size_t)BB * NN;
    float* CTB   = CTA   + (size_t)BB * NCH * FEAT;
    float* PA    = CTB   + (size_t)BB * NCH * FEAT;      // 8 MB
    float* PB    = PA    + (size_t)BB * NN * FEAT;       // 8 MB
    // overlay: Wh/Wl share bytes with PA/PB (disjoint lifetimes)
    ushort* Wh   = (ushort*)PA;                          // 8 MB
    ushort* Wl   = Wh + (size_t)NN * NN;                 // 8 MB
    ushort* xh   = (ushort*)(PB + (size_t)BB * NN * FEAT);  // 4 MB
    ushort* xl   = xh + (size_t)BB * NN * FEAT;             // 4 MB

    const size_t need_mfma =
        (size_t)((char*)(xl + (size_t)BB * NN * FEAT) - (char*)d_ws);
    const bool use_mfma = ws_size >= need_mfma;   // call-invariant -> graph-safe

    k0_ntilde<<<dim3(BB * NN / 256), dim3(256), 0, stream>>>(n, att2, nt);
    if (use_mfma) {
        k_cvtW<<<dim3(NN * NN / 1024), dim3(256), 0, stream>>>(conv_w, Wh, Wl);
        k_cvtX<<<dim3(NN / 64, BB), dim3(256), 0, stream>>>(x, xh, xl);
        k1_mfma<<<dim3(NN / 128, BB), dim3(256), 0, stream>>>(Wh, Wl, xh, xl,
                                                              conv_b, xf);
    } else {
        k1_conv<<<dim3(NN / BM, BB), dim3(256), 0, stream>>>(x, conv_w, conv_b, xf);
    }
    k2_s2<<<dim3(NN * BB / 256), dim3(256), 0, stream>>>(conv_w, nt, conv_b, att2, s2);
    k2b_s1<<<dim3(BB * NN / 256), dim3(256), 0, stream>>>(xf, att1, s1);
    ksort<<<dim3(2, BB), dim3(1024), 0, stream>>>(s1, s2, s1s, p1, s2s, E1suf, E2);
    k_ab<<<dim3(BB * NN / 256), dim3(256), 0, stream>>>(s1s, s2s, E1suf, E2, as, bs);
    kscanA<<<dim3(NCH, BB), dim3(64), 0, stream>>>(p1, as, bs, xf, CTA, CTB);
    kscanB<<<dim3(NCH, BB), dim3(64), 0, stream>>>(p1, as, bs, xf, CTA, CTB, PA, PB);
    k4_sep<<<dim3(NN / 16, BB), dim3(256), 0, stream>>>(s2, s1s, PA, PB, outp);
}

// Round 8
// 252.122 us; speedup vs baseline: 1.3444x; 1.3444x over previous
//
#include <hip/hip_runtime.h>
#include <math.h>

// GraphAttn: B=16, N=2048, feat = C*F = 64.
//  xf = W @ x + bias   (per batch, 2048x2048 * 2048x64)
//  s1[b,o] = xf[b,o,:] . att1
//  s2[b,o] = W @ (n . att2) + bias*sum(att2)   [conv linearity]
//  a = leaky_relu(s1[j]+s2[i]); softmax over i; out = a^T-weighted sums of xf
//  Separable softmax via per-batch sort + prefix/suffix scans (R3, proven).
//
// R8: k1_mfma R7 post-mortem: correct but 122us — lambda-captured stg[] array
//     spilled to scratch (VGPR=68, WRITE_SIZE=90MB phantom) + 1 block/CU.
//     Rewrite k1_mfma2: global_load_lds DMA (no reg staging), source-side
//     swizzle (involution, rule #21), 64x64 tile / 512 blocks / 2 per CU,
//     double-buffered LDS + counted vmcnt(8) pipeline (T4), XCD swizzle.
//     Math identical to R7 (hardware-validated: fragments, swizzle, epilogue).

#define BB 16
#define NN 2048
#define FEAT 64
#define BM 64
#define BK 32
#define NCH 16
#define CHL 128

typedef __attribute__((ext_vector_type(8))) short short8v;   // 8 bf16
typedef __attribute__((ext_vector_type(8))) ushort ushort8v;
typedef __attribute__((ext_vector_type(4))) float f32x4;

__device__ __forceinline__ float lrelu(float t) {
    return fmaxf(t, 0.2f * t);
}

__device__ __forceinline__ ushort bf16_rne(float f) {
    unsigned u = __float_as_uint(f);
    unsigned r = u + 0x7FFF + ((u >> 16) & 1);
    return (ushort)(r >> 16);
}
__device__ __forceinline__ float bf16_to_f(ushort h) {
    return __uint_as_float(((unsigned)h) << 16);
}

// async global->LDS, 16B per lane; LDS dest = wave-uniform base + lane*16
__device__ __forceinline__ void gl_lds16(const void* g, void* l) {
    __builtin_amdgcn_global_load_lds(
        (const __attribute__((address_space(1))) unsigned int*)g,
        (__attribute__((address_space(3))) unsigned int*)l,
        16, 0, 0);
}

// ---------------------------------------------------------------- k_cvtW
__global__ __launch_bounds__(256) void k_cvtW(
        const float* __restrict__ W, ushort* __restrict__ Wh,
        ushort* __restrict__ Wl) {
    int idx = (blockIdx.x * 256 + threadIdx.x) * 4;
    float4 w = *(const float4*)(W + idx);
    ushort h0 = bf16_rne(w.x), h1 = bf16_rne(w.y),
           h2 = bf16_rne(w.z), h3 = bf16_rne(w.w);
    ushort l0 = bf16_rne(w.x - bf16_to_f(h0)), l1 = bf16_rne(w.y - bf16_to_f(h1)),
           l2 = bf16_rne(w.z - bf16_to_f(h2)), l3 = bf16_rne(w.w - bf16_to_f(h3));
    *(ushort4*)(Wh + idx) = make_ushort4(h0, h1, h2, h3);
    *(ushort4*)(Wl + idx) = make_ushort4(l0, l1, l2, l3);
}

// ---------------------------------------------------------------- k_cvtX
// x [b][k][f] fp32 -> xh,xl [b][f][k] bf16 (transposed for B-operand reads)
__global__ __launch_bounds__(256) void k_cvtX(
        const float* __restrict__ x, ushort* __restrict__ xh,
        ushort* __restrict__ xl) {
    __shared__ float tile[64][65];
    const int k0 = blockIdx.x * 64, b = blockIdx.y, t = threadIdx.x;
#pragma unroll
    for (int i = 0; i < 4; ++i) {
        int row = (t >> 4) + i * 16, c4 = (t & 15) * 4;
        *(float4*)&tile[row][c4] =
            *(const float4*)(x + ((size_t)b * NN + k0 + row) * FEAT + c4);
    }
    __syncthreads();
    const int f = t >> 2, kg = t & 3;
    ushort hi[16], lo[16];
#pragma unroll
    for (int e = 0; e < 16; ++e) {
        float v = tile[kg * 16 + e][f];
        ushort h = bf16_rne(v);
        hi[e] = h;
        lo[e] = bf16_rne(v - bf16_to_f(h));
    }
    size_t base = ((size_t)b * FEAT + f) * NN + k0 + kg * 16;
#pragma unroll
    for (int q = 0; q < 2; ++q) {
        ushort8v vh, vl;
#pragma unroll
        for (int e = 0; e < 8; ++e) { vh[e] = hi[q * 8 + e]; vl[e] = lo[q * 8 + e]; }
        *(ushort8v*)(xh + base + q * 8) = vh;
        *(ushort8v*)(xl + base + q * 8) = vl;
    }
}

// ---------------------------------------------------------------- k1_mfma2
// 64 rows x 64 cols per block, 512 blocks (2/CU), 4 waves of 32x32.
// LDS/buffer: Wh 8K | Wl 8K | Xh 8K | Xl 8K = 32K, double-buffered = 64K.
// DMA staging: linear LDS dest, source k-offset pre-swizzled by gc^(row&7)
// (involution; read side XORs byte offset by (row&7)<<4 — proven in R7).
__device__ __forceinline__ void stage_tile(
        const ushort* __restrict__ Wh, const ushort* __restrict__ Wl,
        const ushort* __restrict__ xh, const ushort* __restrict__ xl,
        int wrow0, int xrow0, int k0, char* ldsbuf, int wave, int lane) {
    const int rc = lane >> 3;                       // row within 8-row chunk
    const int kk = ((lane & 7) ^ rc) << 3;          // pre-swizzled k elem-offset
#pragma unroll
    for (int q = 0; q < 2; ++q) {
        const int c = wave * 2 + q;                 // chunk 0..7 (wave-uniform)
        const size_t wr = (size_t)(wrow0 + c * 8 + rc) * NN + k0 + kk;
        const size_t xr = (size_t)(xrow0 + c * 8 + rc) * NN + k0 + kk;
        char* ldc = ldsbuf + c * 1024;
        gl_lds16(Wh + wr, ldc);
        gl_lds16(Wl + wr, ldc + 8192);
        gl_lds16(xh + xr, ldc + 16384);
        gl_lds16(xl + xr, ldc + 24576);
    }
}

#define COMPUTE_TILE(BUF)                                                     \
    {                                                                         \
        const char* bp = (BUF);                                               \
        _Pragma("unroll")                                                     \
        for (int s = 0; s < 2; ++s) {                                         \
            const int kslot = s * 4 + kq;                                     \
            int rowA0 = wr + col, rowA1 = wr + 16 + col;                      \
            int offA0 = (rowA0 * 128 + kslot * 16) ^ ((rowA0 & 7) << 4);      \
            int offA1 = (rowA1 * 128 + kslot * 16) ^ ((rowA1 & 7) << 4);      \
            short8v Ah0 = *(const short8v*)(bp + offA0);                      \
            short8v Ah1 = *(const short8v*)(bp + offA1);                      \
            short8v Al0 = *(const short8v*)(bp + 8192 + offA0);               \
            short8v Al1 = *(const short8v*)(bp + 8192 + offA1);               \
            int fB0 = wc + col, fB1 = wc + 16 + col;                          \
            int offB0 = (fB0 * 128 + kslot * 16) ^ ((fB0 & 7) << 4);          \
            int offB1 = (fB1 * 128 + kslot * 16) ^ ((fB1 & 7) << 4);          \
            short8v Bh0 = *(const short8v*)(bp + 16384 + offB0);              \
            short8v Bh1 = *(const short8v*)(bp + 16384 + offB1);              \
            short8v Bl0 = *(const short8v*)(bp + 24576 + offB0);              \
            short8v Bl1 = *(const short8v*)(bp + 24576 + offB1);              \
            a00 = __builtin_amdgcn_mfma_f32_16x16x32_bf16(Ah0, Bh0, a00, 0, 0, 0); \
            a00 = __builtin_amdgcn_mfma_f32_16x16x32_bf16(Ah0, Bl0, a00, 0, 0, 0); \
            a00 = __builtin_amdgcn_mfma_f32_16x16x32_bf16(Al0, Bh0, a00, 0, 0, 0); \
            a01 = __builtin_amdgcn_mfma_f32_16x16x32_bf16(Ah0, Bh1, a01, 0, 0, 0); \
            a01 = __builtin_amdgcn_mfma_f32_16x16x32_bf16(Ah0, Bl1, a01, 0, 0, 0); \
            a01 = __builtin_amdgcn_mfma_f32_16x16x32_bf16(Al0, Bh1, a01, 0, 0, 0); \
            a10 = __builtin_amdgcn_mfma_f32_16x16x32_bf16(Ah1, Bh0, a10, 0, 0, 0); \
            a10 = __builtin_amdgcn_mfma_f32_16x16x32_bf16(Ah1, Bl0, a10, 0, 0, 0); \
            a10 = __builtin_amdgcn_mfma_f32_16x16x32_bf16(Al1, Bh0, a10, 0, 0, 0); \
            a11 = __builtin_amdgcn_mfma_f32_16x16x32_bf16(Ah1, Bh1, a11, 0, 0, 0); \
            a11 = __builtin_amdgcn_mfma_f32_16x16x32_bf16(Ah1, Bl1, a11, 0, 0, 0); \
            a11 = __builtin_amdgcn_mfma_f32_16x16x32_bf16(Al1, Bh1, a11, 0, 0, 0); \
        }                                                                     \
    }

__global__ __launch_bounds__(256, 2) void k1_mfma2(
        const ushort* __restrict__ Wh, const ushort* __restrict__ Wl,
        const ushort* __restrict__ xh, const ushort* __restrict__ xl,
        const float* __restrict__ bias, float* __restrict__ xf) {
    __shared__ __align__(16) char lds[65536];
    // XCD-aware swizzle: batch pair {2x,2x+1} pinned to XCD x (X tiles L2-fit)
    const int bid = blockIdx.x;                 // 0..511
    const int xcd = bid & 7, j = bid >> 3;
    const int b   = xcd * 2 + (j & 1);
    const int rt0 = (j >> 1) * 64;              // output-row tile base
    const int t = threadIdx.x, wave = t >> 6, lane = t & 63;
    const int wr = (wave >> 1) * 32, wc = (wave & 1) * 32;
    const int col = lane & 15, kq = lane >> 4;  // fragment col / k-quarter
    const int xrow0 = b * FEAT;                 // xh/xl row base ([b][f][k])

    f32x4 a00 = {}, a01 = {}, a10 = {}, a11 = {};

    stage_tile(Wh, Wl, xh, xl, rt0, xrow0, 0, lds, wave, lane);
    for (int kt = 0; kt < 31; ++kt) {
        stage_tile(Wh, Wl, xh, xl, rt0, xrow0, (kt + 1) * 64,
                   lds + ((kt + 1) & 1) * 32768, wave, lane);
        // wait for current tile's 8 DMA loads; next tile's 8 stay in flight
        asm volatile("s_waitcnt vmcnt(8)" ::: "memory");
        __builtin_amdgcn_s_barrier();
        COMPUTE_TILE(lds + (kt & 1) * 32768);
        asm volatile("s_waitcnt lgkmcnt(0)" ::: "memory");
        __builtin_amdgcn_s_barrier();
    }
    asm volatile("s_waitcnt vmcnt(0)" ::: "memory");
    __builtin_amdgcn_s_barrier();
    COMPUTE_TILE(lds + 32768);   // tile 31 -> buffer 1

    // epilogue: C/D layout col=lane&15, row=(lane>>4)*4+r  [R7-proven]
    const size_t obase = (size_t)b * NN + rt0;
#pragma unroll
    for (int r = 0; r < 4; ++r) {
        const int oA = wr + kq * 4 + r;         // rt=0 row within 64-tile
        const int oB = oA + 16;                 // rt=1
        const float bA = bias[rt0 + oA], bB = bias[rt0 + oB];
        xf[(obase + oA) * FEAT + wc + col]      = a00[r] + bA;
        xf[(obase + oA) * FEAT + wc + 16 + col] = a01[r] + bA;
        xf[(obase + oB) * FEAT + wc + col]      = a10[r] + bB;
        xf[(obase + oB) * FEAT + wc + 16 + col] = a11[r] + bB;
    }
}

// ---------------------------------------------------------------- k1_conv (fallback, R3-proven)
__global__ __launch_bounds__(256) void k1_conv(
        const float* __restrict__ x, const float* __restrict__ W,
        const float* __restrict__ bias, float* __restrict__ xf) {
    __shared__ float Ws[BK][BM + 4];
    __shared__ float Xs[BK][FEAT];
    const int o0 = blockIdx.x * BM;
    const int b  = blockIdx.y;
    const int t  = threadIdx.x;
    const int ty = t >> 4, tx = t & 15;
    float acc[4][4] = {};
    for (int k0 = 0; k0 < NN; k0 += BK) {
#pragma unroll
        for (int r = 0; r < 2; ++r) {
            int v = t + r * 256;
            int m = v >> 3, k = (v & 7) * 4;
            float4 w4 = *(const float4*)(W + (size_t)(o0 + m) * NN + k0 + k);
            Ws[k + 0][m] = w4.x; Ws[k + 1][m] = w4.y;
            Ws[k + 2][m] = w4.z; Ws[k + 3][m] = w4.w;
        }
#pragma unroll
        for (int r = 0; r < 2; ++r) {
            int v = t + r * 256;
            int k = v >> 4, hw = (v & 15) * 4;
            *(float4*)&Xs[k][hw] =
                *(const float4*)(x + ((size_t)b * NN + k0 + k) * FEAT + hw);
        }
        __syncthreads();
#pragma unroll
        for (int kk = 0; kk < BK; ++kk) {
            float a[4], c[4];
            *(float4*)a = *(const float4*)&Ws[kk][ty * 4];
            *(float4*)c = *(const float4*)&Xs[kk][tx * 4];
#pragma unroll
            for (int ii = 0; ii < 4; ++ii)
#pragma unroll
                for (int ff = 0; ff < 4; ++ff)
                    acc[ii][ff] += a[ii] * c[ff];
        }
        __syncthreads();
    }
#pragma unroll
    for (int ii = 0; ii < 4; ++ii) {
        int o = o0 + ty * 4 + ii;
        float bv = bias[o];
        float4 r = make_float4(acc[ii][0] + bv, acc[ii][1] + bv,
                               acc[ii][2] + bv, acc[ii][3] + bv);
        *(float4*)(xf + ((size_t)b * NN + o) * FEAT + tx * 4) = r;
    }
}

// ---------------------------------------------------------------- k0: ntilde
__global__ __launch_bounds__(256) void k0_ntilde(
        const float* __restrict__ n, const float* __restrict__ att2,
        float* __restrict__ nt) {
    int t = blockIdx.x * 256 + threadIdx.x;
    int b = t >> 11, i = t & (NN - 1);
    const float4* row = (const float4*)(n + ((size_t)b * NN + i) * FEAT);
    const float4* a2  = (const float4*)att2;
    float s = 0.f;
#pragma unroll
    for (int q = 0; q < 16; ++q) {
        float4 v = row[q], w = a2[q];
        s += v.x * w.x + v.y * w.y + v.z * w.z + v.w * w.w;
    }
    nt[i * BB + b] = s;
}

// ---------------------------------------------------------------- k2: s2
__global__ __launch_bounds__(256) void k2_s2(
        const float* __restrict__ W, const float* __restrict__ nt,
        const float* __restrict__ bias, const float* __restrict__ att2,
        float* __restrict__ s2) {
    int t = blockIdx.x * 256 + threadIdx.x;
    int o = t >> 4, b = t & 15;
    float acc = 0.f;
    for (int i = 0; i < NN; i += 4) {
        float4 w4 = *(const float4*)(W + (size_t)o * NN + i);
        acc += w4.x * nt[(i + 0) * BB + b] + w4.y * nt[(i + 1) * BB + b]
             + w4.z * nt[(i + 2) * BB + b] + w4.w * nt[(i + 3) * BB + b];
    }
    float A2 = 0.f;
#pragma unroll
    for (int q = 0; q < FEAT; ++q) A2 += att2[q];
    s2[(size_t)b * NN + o] = acc + bias[o] * A2;
}

// ---------------------------------------------------------------- k2b: s1
__global__ __launch_bounds__(256) void k2b_s1(
        const float* __restrict__ xf, const float* __restrict__ att1,
        float* __restrict__ s1) {
    int t = blockIdx.x * 256 + threadIdx.x;
    const float4* row = (const float4*)(xf + (size_t)t * FEAT);
    const float4* a1  = (const float4*)att1;
    float s = 0.f;
#pragma unroll
    for (int q = 0; q < 16; ++q) {
        float4 v = row[q], w = a1[q];
        s += v.x * w.x + v.y * w.y + v.z * w.z + v.w * w.w;
    }
    s1[t] = s;
}

// ---------------------------------------------------------------- sort+scan
__device__ __forceinline__ void scan2048(float* buf, int t) {
    for (int off = 1; off < 2048; off <<= 1) {
        int i0 = t, i1 = t + 1024;
        float x0 = (i0 >= off) ? buf[i0 - off] : 0.f;
        float c0 = buf[i0];
        float x1 = (i1 >= off) ? buf[i1 - off] : 0.f;
        float c1 = buf[i1];
        __syncthreads();
        buf[i0] = c0 + x0;
        buf[i1] = c1 + x1;
        __syncthreads();
    }
}

__global__ __launch_bounds__(1024) void ksort(
        const float* __restrict__ s1, const float* __restrict__ s2,
        float* __restrict__ s1s, int* __restrict__ p1,
        float* __restrict__ s2s, float* __restrict__ E1suf,
        float* __restrict__ E2) {
    __shared__ float key[2048];
    __shared__ int   val[2048];
    __shared__ float buf[2048];
    const int b = blockIdx.y, arr = blockIdx.x, t = threadIdx.x;
    const float* src = (arr == 0 ? s1 : s2) + (size_t)b * NN;
    key[t] = src[t]; key[t + 1024] = src[t + 1024];
    val[t] = t;      val[t + 1024] = t + 1024;
    __syncthreads();
    for (int k = 2; k <= 2048; k <<= 1) {
        for (int j = k >> 1; j > 0; j >>= 1) {
#pragma unroll
            for (int r = 0; r < 2; ++r) {
                int i = r * 1024 + t;
                int l = i ^ j;
                if (l > i) {
                    bool up = ((i & k) == 0);
                    float ki = key[i], kl = key[l];
                    if (up ? (ki > kl) : (ki < kl)) {
                        key[i] = kl; key[l] = ki;
                        int vi = val[i]; val[i] = val[l]; val[l] = vi;
                    }
                }
            }
            __syncthreads();
        }
    }
    const size_t base = (size_t)b * NN;
    if (arr == 0) {
        s1s[base + t] = key[t]; s1s[base + t + 1024] = key[t + 1024];
        p1[base + t]  = val[t]; p1[base + t + 1024]  = val[t + 1024];
    } else {
        s2s[base + t] = key[t]; s2s[base + t + 1024] = key[t + 1024];
        buf[t] = __expf(0.2f * key[t]);
        buf[t + 1024] = __expf(0.2f * key[t + 1024]);
        __syncthreads();
        scan2048(buf, t);
        E2[base + t] = buf[t]; E2[base + t + 1024] = buf[t + 1024];
        __syncthreads();
        buf[t] = __expf(key[2047 - t]);
        buf[t + 1024] = __expf(key[2047 - (t + 1024)]);
        __syncthreads();
        scan2048(buf, t);
        E1suf[base + 2047 - t] = buf[t];
        E1suf[base + 2047 - (t + 1024)] = buf[t + 1024];
    }
}

// ---------------------------------------------------------------- k_ab
__global__ __launch_bounds__(256) void k_ab(
        const float* __restrict__ s1s, const float* __restrict__ s2s,
        const float* __restrict__ E1suf, const float* __restrict__ E2,
        float* __restrict__ as, float* __restrict__ bs) {
    int idx = blockIdx.x * 256 + threadIdx.x;
    int b = idx >> 11;
    const size_t base = (size_t)b * NN;
    float s1v = s1s[idx];
    float thr = -s1v;
    const float* S2 = s2s + base;
    int lo = 0, hi = NN;
    while (lo < hi) { int mid = (lo + hi) >> 1; if (S2[mid] < thr) lo = mid + 1; else hi = mid; }
    float e1 = (lo < NN) ? E1suf[base + lo] : 0.f;
    float e2 = (lo > 0)  ? E2[base + lo - 1] : 0.f;
    float ea = __expf(s1v), eb = __expf(0.2f * s1v);
    float zi = 1.0f / (ea * e1 + eb * e2);
    as[idx] = ea * zi;
    bs[idx] = eb * zi;
}

// ---------------------------------------------------------------- scans
__global__ __launch_bounds__(64) void kscanA(
        const int* __restrict__ p1, const float* __restrict__ as,
        const float* __restrict__ bs, const float* __restrict__ xf,
        float* __restrict__ CTA, float* __restrict__ CTB) {
    const int b = blockIdx.y, c = blockIdx.x, f = threadIdx.x;
    const size_t base = (size_t)b * NN;
    float sA = 0.f, sB = 0.f;
#pragma unroll 8
    for (int r = 0; r < CHL; ++r) {
        int t = c * CHL + r;
        int j = p1[base + t];
        float xv = xf[(base + j) * FEAT + f];
        sA += as[base + t] * xv;
        sB += bs[base + t] * xv;
    }
    CTA[((size_t)b * NCH + c) * FEAT + f] = sA;
    CTB[((size_t)b * NCH + c) * FEAT + f] = sB;
}

__global__ __launch_bounds__(64) void kscanB(
        const int* __restrict__ p1, const float* __restrict__ as,
        const float* __restrict__ bs, const float* __restrict__ xf,
        const float* __restrict__ CTA, const float* __restrict__ CTB,
        float* __restrict__ PA, float* __restrict__ PB) {
    const int b = blockIdx.y, c = blockIdx.x, f = threadIdx.x;
    const size_t base = (size_t)b * NN;
    float offA = 0.f, offB = 0.f;
    for (int cc = 0; cc < NCH; ++cc) {
        float av = CTA[((size_t)b * NCH + cc) * FEAT + f];
        float bv = CTB[((size_t)b * NCH + cc) * FEAT + f];
        if (cc > c) offA += av;
        if (cc < c) offB += bv;
    }
    float run = offB;
#pragma unroll 4
    for (int r = 0; r < CHL; ++r) {
        int t = c * CHL + r;
        int j = p1[base + t];
        float xv = xf[(base + j) * FEAT + f];
        run += bs[base + t] * xv;
        PB[(base + t) * FEAT + f] = run;
    }
    run = offA;
#pragma unroll 4
    for (int r = CHL - 1; r >= 0; --r) {
        int t = c * CHL + r;
        int j = p1[base + t];
        float xv = xf[(base + j) * FEAT + f];
        run += as[base + t] * xv;
        PA[(base + t) * FEAT + f] = run;
    }
}

// ---------------------------------------------------------------- k4
__global__ __launch_bounds__(256) void k4_sep(
        const float* __restrict__ s2, const float* __restrict__ s1s,
        const float* __restrict__ PA, const float* __restrict__ PB,
        float* __restrict__ out) {
    const int b = blockIdx.y;
    const int i = blockIdx.x * 16 + (threadIdx.x >> 4);
    const int fg = threadIdx.x & 15;
    const size_t base = (size_t)b * NN;
    float s2v = s2[base + i];
    float thr = -s2v;
    const float* S1 = s1s + base;
    int lo = 0, hi = NN;
    while (lo < hi) { int mid = (lo + hi) >> 1; if (S1[mid] < thr) lo = mid + 1; else hi = mid; }
    float eA = __expf(s2v), eB = __expf(0.2f * s2v);
    float4 pa = make_float4(0.f, 0.f, 0.f, 0.f);
    float4 pb = make_float4(0.f, 0.f, 0.f, 0.f);
    if (lo < NN) pa = *(const float4*)(PA + (base + lo) * FEAT + fg * 4);
    if (lo > 0)  pb = *(const float4*)(PB + (base + lo - 1) * FEAT + fg * 4);
    float4 o;
    o.x = eA * pa.x + eB * pb.x;
    o.y = eA * pa.y + eB * pb.y;
    o.z = eA * pa.z + eB * pb.z;
    o.w = eA * pa.w + eB * pb.w;
    *(float4*)(out + (base + i) * FEAT + fg * 4) = o;
}

extern "C" void kernel_launch(void* const* d_in, const int* in_sizes, int n_in,
                              void* d_out, int out_size, void* d_ws, size_t ws_size,
                              hipStream_t stream) {
    const float* x      = (const float*)d_in[0];
    const float* n      = (const float*)d_in[1];
    const float* conv_w = (const float*)d_in[2];
    const float* conv_b = (const float*)d_in[3];
    const float* att1   = (const float*)d_in[4];
    const float* att2   = (const float*)d_in[5];
    float* outp = (float*)d_out;
    float* xf = outp;   // xf aliases d_out (k4_sep overwrites all of it)

    // ---- ws layout: smalls | PA/PB (overlay Wh/Wl) | xh/xl
    float* ws    = (float*)d_ws;
    float* s1    = ws;
    float* s2    = s1    + (size_t)BB * NN;
    float* nt    = s2    + (size_t)BB * NN;
    float* s1s   = nt    + (size_t)BB * NN;
    int*   p1    = (int*)(s1s + (size_t)BB * NN);
    float* s2s   = (float*)p1 + (size_t)BB * NN;
    float* E1suf = s2s   + (size_t)BB * NN;
    float* E2    = E1suf + (size_t)BB * NN;
    float* as    = E2    + (size_t)BB * NN;
    float* bs    = as    + (size_t)BB * NN;
    float* CTA   = bs    + (size_t)BB * NN;
    float* CTB   = CTA   + (size_t)BB * NCH * FEAT;
    float* PA    = CTB   + (size_t)BB * NCH * FEAT;      // 8 MB
    float* PB    = PA    + (size_t)BB * NN * FEAT;       // 8 MB
    // overlay: Wh/Wl share bytes with PA/PB (disjoint lifetimes)
    ushort* Wh   = (ushort*)PA;                          // 8 MB
    ushort* Wl   = Wh + (size_t)NN * NN;                 // 8 MB
    ushort* xh   = (ushort*)(PB + (size_t)BB * NN * FEAT);  // 4 MB
    ushort* xl   = xh + (size_t)BB * NN * FEAT;             // 4 MB

    const size_t need_mfma =
        (size_t)((char*)(xl + (size_t)BB * NN * FEAT) - (char*)d_ws);
    const bool use_mfma = ws_size >= need_mfma;   // call-invariant -> graph-safe

    k0_ntilde<<<dim3(BB * NN / 256), dim3(256), 0, stream>>>(n, att2, nt);
    if (use_mfma) {
        k_cvtW<<<dim3(NN * NN / 1024), dim3(256), 0, stream>>>(conv_w, Wh, Wl);
        k_cvtX<<<dim3(NN / 64, BB), dim3(256), 0, stream>>>(x, xh, xl);
        k1_mfma2<<<dim3(512), dim3(256), 0, stream>>>(Wh, Wl, xh, xl,
                                                      conv_b, xf);
    } else {
        k1_conv<<<dim3(NN / BM, BB), dim3(256), 0, stream>>>(x, conv_w, conv_b, xf);
    }
    k2_s2<<<dim3(NN * BB / 256), dim3(256), 0, stream>>>(conv_w, nt, conv_b, att2, s2);
    k2b_s1<<<dim3(BB * NN / 256), dim3(256), 0, stream>>>(xf, att1, s1);
    ksort<<<dim3(2, BB), dim3(1024), 0, stream>>>(s1, s2, s1s, p1, s2s, E1suf, E2);
    k_ab<<<dim3(BB * NN / 256), dim3(256), 0, stream>>>(s1s, s2s, E1suf, E2, as, bs);
    kscanA<<<dim3(NCH, BB), dim3(64), 0, stream>>>(p1, as, bs, xf, CTA, CTB);
    kscanB<<<dim3(NCH, BB), dim3(64), 0, stream>>>(p1, as, bs, xf, CTA, CTB, PA, PB);
    k4_sep<<<dim3(NN / 16, BB), dim3(256), 0, stream>>>(s2, s1s, PA, PB, outp);
}

// Round 10
// 217.638 us; speedup vs baseline: 1.5574x; 1.1584x over previous
//
#include <hip/hip_runtime.h>
#include <math.h>

// GraphAttn: B=16, N=2048, feat = C*F = 64.
//  xf = W @ x + bias   (per batch, 2048x2048 * 2048x64)
//  s1[b,o] = xf[b,o,:] . att1
//  s2[b,o] = W @ (n . att2) + bias*sum(att2)   [conv linearity]
//  a = leaky_relu(s1[j]+s2[i]); softmax over i; out = a^T-weighted sums of xf
//  Separable softmax via per-batch sort + prefix/suffix scans (R3, proven).
//
// R10 == R9 resubmit (R9 never ran: GPU acquisition timeout).
// k2_s2 (49.6us, latency-bound, occ 5%) folded into k1_mfma2 as a 17th
// "batch" whose B-operand is nth/ntl (bf16 hi/lo of nt, [b][i] layout).
// Same 3-term split => s2 = Wh@nth + Wh@ntl + Wl@nth + bias*sum(att2).
// Epilogue writes s2[col*NN+o] for b==16 (cols 16..63 discarded; junk
// staging rows only touch discarded output columns). Grid 512->544.

#define BB 16
#define NN 2048
#define FEAT 64
#define BM 64
#define BK 32
#define NCH 16
#define CHL 128

typedef __attribute__((ext_vector_type(8))) short short8v;   // 8 bf16
typedef __attribute__((ext_vector_type(8))) ushort ushort8v;
typedef __attribute__((ext_vector_type(4))) float f32x4;

__device__ __forceinline__ float lrelu(float t) {
    return fmaxf(t, 0.2f * t);
}

__device__ __forceinline__ ushort bf16_rne(float f) {
    unsigned u = __float_as_uint(f);
    unsigned r = u + 0x7FFF + ((u >> 16) & 1);
    return (ushort)(r >> 16);
}
__device__ __forceinline__ float bf16_to_f(ushort h) {
    return __uint_as_float(((unsigned)h) << 16);
}

// async global->LDS, 16B per lane; LDS dest = wave-uniform base + lane*16
__device__ __forceinline__ void gl_lds16(const void* g, void* l) {
    __builtin_amdgcn_global_load_lds(
        (const __attribute__((address_space(1))) unsigned int*)g,
        (__attribute__((address_space(3))) unsigned int*)l,
        16, 0, 0);
}

// ---------------------------------------------------------------- k_cvtW
__global__ __launch_bounds__(256) void k_cvtW(
        const float* __restrict__ W, ushort* __restrict__ Wh,
        ushort* __restrict__ Wl) {
    int idx = (blockIdx.x * 256 + threadIdx.x) * 4;
    float4 w = *(const float4*)(W + idx);
    ushort h0 = bf16_rne(w.x), h1 = bf16_rne(w.y),
           h2 = bf16_rne(w.z), h3 = bf16_rne(w.w);
    ushort l0 = bf16_rne(w.x - bf16_to_f(h0)), l1 = bf16_rne(w.y - bf16_to_f(h1)),
           l2 = bf16_rne(w.z - bf16_to_f(h2)), l3 = bf16_rne(w.w - bf16_to_f(h3));
    *(ushort4*)(Wh + idx) = make_ushort4(h0, h1, h2, h3);
    *(ushort4*)(Wl + idx) = make_ushort4(l0, l1, l2, l3);
}

// ---------------------------------------------------------------- k_cvtX
// x [b][k][f] fp32 -> xh,xl [b][f][k] bf16 (transposed for B-operand reads)
__global__ __launch_bounds__(256) void k_cvtX(
        const float* __restrict__ x, ushort* __restrict__ xh,
        ushort* __restrict__ xl) {
    __shared__ float tile[64][65];
    const int k0 = blockIdx.x * 64, b = blockIdx.y, t = threadIdx.x;
#pragma unroll
    for (int i = 0; i < 4; ++i) {
        int row = (t >> 4) + i * 16, c4 = (t & 15) * 4;
        *(float4*)&tile[row][c4] =
            *(const float4*)(x + ((size_t)b * NN + k0 + row) * FEAT + c4);
    }
    __syncthreads();
    const int f = t >> 2, kg = t & 3;
    ushort hi[16], lo[16];
#pragma unroll
    for (int e = 0; e < 16; ++e) {
        float v = tile[kg * 16 + e][f];
        ushort h = bf16_rne(v);
        hi[e] = h;
        lo[e] = bf16_rne(v - bf16_to_f(h));
    }
    size_t base = ((size_t)b * FEAT + f) * NN + k0 + kg * 16;
#pragma unroll
    for (int q = 0; q < 2; ++q) {
        ushort8v vh, vl;
#pragma unroll
        for (int e = 0; e < 8; ++e) { vh[e] = hi[q * 8 + e]; vl[e] = lo[q * 8 + e]; }
        *(ushort8v*)(xh + base + q * 8) = vh;
        *(ushort8v*)(xl + base + q * 8) = vl;
    }
}

// ---------------------------------------------------------------- k0: ntilde
// nt fp32 [i][b] (fallback path) + nth/ntl bf16 [b][i] (MFMA batch-16 operand)
__global__ __launch_bounds__(256) void k0_ntilde(
        const float* __restrict__ n, const float* __restrict__ att2,
        float* __restrict__ nt, ushort* __restrict__ nth,
        ushort* __restrict__ ntl, int wbf) {
    int t = blockIdx.x * 256 + threadIdx.x;
    int b = t >> 11, i = t & (NN - 1);
    const float4* row = (const float4*)(n + ((size_t)b * NN + i) * FEAT);
    const float4* a2  = (const float4*)att2;
    float s = 0.f;
#pragma unroll
    for (int q = 0; q < 16; ++q) {
        float4 v = row[q], w = a2[q];
        s += v.x * w.x + v.y * w.y + v.z * w.z + v.w * w.w;
    }
    nt[i * BB + b] = s;
    if (wbf) {
        ushort h = bf16_rne(s);
        nth[(size_t)b * NN + i] = h;
        ntl[(size_t)b * NN + i] = bf16_rne(s - bf16_to_f(h));
    }
}

// ---------------------------------------------------------------- k1_mfma2
// 64x64 tile, 4 waves of 32x32, double-buffered LDS + counted vmcnt(8).
// bid<512: batch b, output tile of xf.  bid>=512: virtual batch 16 whose
// B-operand rows are nth/ntl (placed at xh/xl row offset 1024) -> writes s2.
__device__ __forceinline__ void stage_tile(
        const ushort* __restrict__ Wh, const ushort* __restrict__ Wl,
        const ushort* __restrict__ xh, const ushort* __restrict__ xl,
        int wrow0, int xrow0, int k0, char* ldsbuf, int wave, int lane) {
    const int rc = lane >> 3;                       // row within 8-row chunk
    const int kk = ((lane & 7) ^ rc) << 3;          // pre-swizzled k elem-offset
#pragma unroll
    for (int q = 0; q < 2; ++q) {
        const int c = wave * 2 + q;                 // chunk 0..7 (wave-uniform)
        const size_t wr = (size_t)(wrow0 + c * 8 + rc) * NN + k0 + kk;
        const size_t xr = (size_t)(xrow0 + c * 8 + rc) * NN + k0 + kk;
        char* ldc = ldsbuf + c * 1024;
        gl_lds16(Wh + wr, ldc);
        gl_lds16(Wl + wr, ldc + 8192);
        gl_lds16(xh + xr, ldc + 16384);
        gl_lds16(xl + xr, ldc + 24576);
    }
}

#define COMPUTE_TILE(BUF)                                                     \
    {                                                                         \
        const char* bp = (BUF);                                               \
        _Pragma("unroll")                                                     \
        for (int s = 0; s < 2; ++s) {                                         \
            const int kslot = s * 4 + kq;                                     \
            int rowA0 = wr + col, rowA1 = wr + 16 + col;                      \
            int offA0 = (rowA0 * 128 + kslot * 16) ^ ((rowA0 & 7) << 4);      \
            int offA1 = (rowA1 * 128 + kslot * 16) ^ ((rowA1 & 7) << 4);      \
            short8v Ah0 = *(const short8v*)(bp + offA0);                      \
            short8v Ah1 = *(const short8v*)(bp + offA1);                      \
            short8v Al0 = *(const short8v*)(bp + 8192 + offA0);               \
            short8v Al1 = *(const short8v*)(bp + 8192 + offA1);               \
            int fB0 = wc + col, fB1 = wc + 16 + col;                          \
            int offB0 = (fB0 * 128 + kslot * 16) ^ ((fB0 & 7) << 4);          \
            int offB1 = (fB1 * 128 + kslot * 16) ^ ((fB1 & 7) << 4);          \
            short8v Bh0 = *(const short8v*)(bp + 16384 + offB0);              \
            short8v Bh1 = *(const short8v*)(bp + 16384 + offB1);              \
            short8v Bl0 = *(const short8v*)(bp + 24576 + offB0);              \
            short8v Bl1 = *(const short8v*)(bp + 24576 + offB1);              \
            a00 = __builtin_amdgcn_mfma_f32_16x16x32_bf16(Ah0, Bh0, a00, 0, 0, 0); \
            a00 = __builtin_amdgcn_mfma_f32_16x16x32_bf16(Ah0, Bl0, a00, 0, 0, 0); \
            a00 = __builtin_amdgcn_mfma_f32_16x16x32_bf16(Al0, Bh0, a00, 0, 0, 0); \
            a01 = __builtin_amdgcn_mfma_f32_16x16x32_bf16(Ah0, Bh1, a01, 0, 0, 0); \
            a01 = __builtin_amdgcn_mfma_f32_16x16x32_bf16(Ah0, Bl1, a01, 0, 0, 0); \
            a01 = __builtin_amdgcn_mfma_f32_16x16x32_bf16(Al0, Bh1, a01, 0, 0, 0); \
            a10 = __builtin_amdgcn_mfma_f32_16x16x32_bf16(Ah1, Bh0, a10, 0, 0, 0); \
            a10 = __builtin_amdgcn_mfma_f32_16x16x32_bf16(Ah1, Bl0, a10, 0, 0, 0); \
            a10 = __builtin_amdgcn_mfma_f32_16x16x32_bf16(Al1, Bh0, a10, 0, 0, 0); \
            a11 = __builtin_amdgcn_mfma_f32_16x16x32_bf16(Ah1, Bh1, a11, 0, 0, 0); \
            a11 = __builtin_amdgcn_mfma_f32_16x16x32_bf16(Ah1, Bl1, a11, 0, 0, 0); \
            a11 = __builtin_amdgcn_mfma_f32_16x16x32_bf16(Al1, Bh1, a11, 0, 0, 0); \
        }                                                                     \
    }

__global__ __launch_bounds__(256, 2) void k1_mfma2(
        const ushort* __restrict__ Wh, const ushort* __restrict__ Wl,
        const ushort* __restrict__ xh, const ushort* __restrict__ xl,
        const float* __restrict__ bias, const float* __restrict__ att2,
        float* __restrict__ xf, float* __restrict__ s2out) {
    __shared__ __align__(16) char lds[65536];
    const int bid = blockIdx.x;                 // 0..543
    int b, rt0;
    if (bid < 512) {                            // XCD-aware: batch pair per XCD
        const int xcd = bid & 7, j = bid >> 3;
        b   = xcd * 2 + (j & 1);
        rt0 = (j >> 1) * 64;
    } else {                                    // virtual batch: s2 GEMM
        b   = 16;
        rt0 = (bid - 512) * 64;
    }
    const int t = threadIdx.x, wave = t >> 6, lane = t & 63;
    const int wr = (wave >> 1) * 32, wc = (wave & 1) * 32;
    const int col = lane & 15, kq = lane >> 4;  // fragment col / k-quarter
    const int xrow0 = b * FEAT;                 // b==16 -> rows 1024.. = nth/ntl

    f32x4 a00 = {}, a01 = {}, a10 = {}, a11 = {};

    stage_tile(Wh, Wl, xh, xl, rt0, xrow0, 0, lds, wave, lane);
    for (int kt = 0; kt < 31; ++kt) {
        stage_tile(Wh, Wl, xh, xl, rt0, xrow0, (kt + 1) * 64,
                   lds + ((kt + 1) & 1) * 32768, wave, lane);
        asm volatile("s_waitcnt vmcnt(8)" ::: "memory");
        __builtin_amdgcn_s_barrier();
        COMPUTE_TILE(lds + (kt & 1) * 32768);
        asm volatile("s_waitcnt lgkmcnt(0)" ::: "memory");
        __builtin_amdgcn_s_barrier();
    }
    asm volatile("s_waitcnt vmcnt(0)" ::: "memory");
    __builtin_amdgcn_s_barrier();
    COMPUTE_TILE(lds + 32768);   // tile 31 -> buffer 1

    if (b < 16) {
        // epilogue: C/D layout col=lane&15, row=(lane>>4)*4+r  [R7-proven]
        const size_t obase = (size_t)b * NN + rt0;
#pragma unroll
        for (int r = 0; r < 4; ++r) {
            const int oA = wr + kq * 4 + r;
            const int oB = oA + 16;
            const float bA = bias[rt0 + oA], bB = bias[rt0 + oB];
            xf[(obase + oA) * FEAT + wc + col]      = a00[r] + bA;
            xf[(obase + oA) * FEAT + wc + 16 + col] = a01[r] + bA;
            xf[(obase + oB) * FEAT + wc + col]      = a10[r] + bB;
            xf[(obase + oB) * FEAT + wc + 16 + col] = a11[r] + bB;
        }
    } else if (wc == 0) {
        // s2 epilogue: valid cols 0..15 only (col = batch index)
        float A2 = 0.f;
        const float4* a2 = (const float4*)att2;
#pragma unroll
        for (int q = 0; q < 16; ++q) {
            float4 v = a2[q];
            A2 += v.x + v.y + v.z + v.w;
        }
#pragma unroll
        for (int r = 0; r < 4; ++r) {
            const int oA = wr + kq * 4 + r;
            const int oB = oA + 16;
            s2out[(size_t)col * NN + rt0 + oA] = a00[r] + bias[rt0 + oA] * A2;
            s2out[(size_t)col * NN + rt0 + oB] = a10[r] + bias[rt0 + oB] * A2;
        }
    }
}

// ---------------------------------------------------------------- k1_conv (fallback, R3-proven)
__global__ __launch_bounds__(256) void k1_conv(
        const float* __restrict__ x, const float* __restrict__ W,
        const float* __restrict__ bias, float* __restrict__ xf) {
    __shared__ float Ws[BK][BM + 4];
    __shared__ float Xs[BK][FEAT];
    const int o0 = blockIdx.x * BM;
    const int b  = blockIdx.y;
    const int t  = threadIdx.x;
    const int ty = t >> 4, tx = t & 15;
    float acc[4][4] = {};
    for (int k0 = 0; k0 < NN; k0 += BK) {
#pragma unroll
        for (int r = 0; r < 2; ++r) {
            int v = t + r * 256;
            int m = v >> 3, k = (v & 7) * 4;
            float4 w4 = *(const float4*)(W + (size_t)(o0 + m) * NN + k0 + k);
            Ws[k + 0][m] = w4.x; Ws[k + 1][m] = w4.y;
            Ws[k + 2][m] = w4.z; Ws[k + 3][m] = w4.w;
        }
#pragma unroll
        for (int r = 0; r < 2; ++r) {
            int v = t + r * 256;
            int k = v >> 4, hw = (v & 15) * 4;
            *(float4*)&Xs[k][hw] =
                *(const float4*)(x + ((size_t)b * NN + k0 + k) * FEAT + hw);
        }
        __syncthreads();
#pragma unroll
        for (int kk = 0; kk < BK; ++kk) {
            float a[4], c[4];
            *(float4*)a = *(const float4*)&Ws[kk][ty * 4];
            *(float4*)c = *(const float4*)&Xs[kk][tx * 4];
#pragma unroll
            for (int ii = 0; ii < 4; ++ii)
#pragma unroll
                for (int ff = 0; ff < 4; ++ff)
                    acc[ii][ff] += a[ii] * c[ff];
        }
        __syncthreads();
    }
#pragma unroll
    for (int ii = 0; ii < 4; ++ii) {
        int o = o0 + ty * 4 + ii;
        float bv = bias[o];
        float4 r = make_float4(acc[ii][0] + bv, acc[ii][1] + bv,
                               acc[ii][2] + bv, acc[ii][3] + bv);
        *(float4*)(xf + ((size_t)b * NN + o) * FEAT + tx * 4) = r;
    }
}

// ---------------------------------------------------------------- k2: s2 (fallback only)
__global__ __launch_bounds__(256) void k2_s2(
        const float* __restrict__ W, const float* __restrict__ nt,
        const float* __restrict__ bias, const float* __restrict__ att2,
        float* __restrict__ s2) {
    int t = blockIdx.x * 256 + threadIdx.x;
    int o = t >> 4, b = t & 15;
    float acc = 0.f;
    for (int i = 0; i < NN; i += 4) {
        float4 w4 = *(const float4*)(W + (size_t)o * NN + i);
        acc += w4.x * nt[(i + 0) * BB + b] + w4.y * nt[(i + 1) * BB + b]
             + w4.z * nt[(i + 2) * BB + b] + w4.w * nt[(i + 3) * BB + b];
    }
    float A2 = 0.f;
#pragma unroll
    for (int q = 0; q < FEAT; ++q) A2 += att2[q];
    s2[(size_t)b * NN + o] = acc + bias[o] * A2;
}

// ---------------------------------------------------------------- k2b: s1
__global__ __launch_bounds__(256) void k2b_s1(
        const float* __restrict__ xf, const float* __restrict__ att1,
        float* __restrict__ s1) {
    int t = blockIdx.x * 256 + threadIdx.x;
    const float4* row = (const float4*)(xf + (size_t)t * FEAT);
    const float4* a1  = (const float4*)att1;
    float s = 0.f;
#pragma unroll
    for (int q = 0; q < 16; ++q) {
        float4 v = row[q], w = a1[q];
        s += v.x * w.x + v.y * w.y + v.z * w.z + v.w * w.w;
    }
    s1[t] = s;
}

// ---------------------------------------------------------------- sort+scan
__device__ __forceinline__ void scan2048(float* buf, int t) {
    for (int off = 1; off < 2048; off <<= 1) {
        int i0 = t, i1 = t + 1024;
        float x0 = (i0 >= off) ? buf[i0 - off] : 0.f;
        float c0 = buf[i0];
        float x1 = (i1 >= off) ? buf[i1 - off] : 0.f;
        float c1 = buf[i1];
        __syncthreads();
        buf[i0] = c0 + x0;
        buf[i1] = c1 + x1;
        __syncthreads();
    }
}

__global__ __launch_bounds__(1024) void ksort(
        const float* __restrict__ s1, const float* __restrict__ s2,
        float* __restrict__ s1s, int* __restrict__ p1,
        float* __restrict__ s2s, float* __restrict__ E1suf,
        float* __restrict__ E2) {
    __shared__ float key[2048];
    __shared__ int   val[2048];
    __shared__ float buf[2048];
    const int b = blockIdx.y, arr = blockIdx.x, t = threadIdx.x;
    const float* src = (arr == 0 ? s1 : s2) + (size_t)b * NN;
    key[t] = src[t]; key[t + 1024] = src[t + 1024];
    val[t] = t;      val[t + 1024] = t + 1024;
    __syncthreads();
    for (int k = 2; k <= 2048; k <<= 1) {
        for (int j = k >> 1; j > 0; j >>= 1) {
#pragma unroll
            for (int r = 0; r < 2; ++r) {
                int i = r * 1024 + t;
                int l = i ^ j;
                if (l > i) {
                    bool up = ((i & k) == 0);
                    float ki = key[i], kl = key[l];
                    if (up ? (ki > kl) : (ki < kl)) {
                        key[i] = kl; key[l] = ki;
                        int vi = val[i]; val[i] = val[l]; val[l] = vi;
                    }
                }
            }
            __syncthreads();
        }
    }
    const size_t base = (size_t)b * NN;
    if (arr == 0) {
        s1s[base + t] = key[t]; s1s[base + t + 1024] = key[t + 1024];
        p1[base + t]  = val[t]; p1[base + t + 1024]  = val[t + 1024];
    } else {
        s2s[base + t] = key[t]; s2s[base + t + 1024] = key[t + 1024];
        buf[t] = __expf(0.2f * key[t]);
        buf[t + 1024] = __expf(0.2f * key[t + 1024]);
        __syncthreads();
        scan2048(buf, t);
        E2[base + t] = buf[t]; E2[base + t + 1024] = buf[t + 1024];
        __syncthreads();
        buf[t] = __expf(key[2047 - t]);
        buf[t + 1024] = __expf(key[2047 - (t + 1024)]);
        __syncthreads();
        scan2048(buf, t);
        E1suf[base + 2047 - t] = buf[t];
        E1suf[base + 2047 - (t + 1024)] = buf[t + 1024];
    }
}

// ---------------------------------------------------------------- k_ab
__global__ __launch_bounds__(256) void k_ab(
        const float* __restrict__ s1s, const float* __restrict__ s2s,
        const float* __restrict__ E1suf, const float* __restrict__ E2,
        float* __restrict__ as, float* __restrict__ bs) {
    int idx = blockIdx.x * 256 + threadIdx.x;
    int b = idx >> 11;
    const size_t base = (size_t)b * NN;
    float s1v = s1s[idx];
    float thr = -s1v;
    const float* S2 = s2s + base;
    int lo = 0, hi = NN;
    while (lo < hi) { int mid = (lo + hi) >> 1; if (S2[mid] < thr) lo = mid + 1; else hi = mid; }
    float e1 = (lo < NN) ? E1suf[base + lo] : 0.f;
    float e2 = (lo > 0)  ? E2[base + lo - 1] : 0.f;
    float ea = __expf(s1v), eb = __expf(0.2f * s1v);
    float zi = 1.0f / (ea * e1 + eb * e2);
    as[idx] = ea * zi;
    bs[idx] = eb * zi;
}

// ---------------------------------------------------------------- scans
__global__ __launch_bounds__(64) void kscanA(
        const int* __restrict__ p1, const float* __restrict__ as,
        const float* __restrict__ bs, const float* __restrict__ xf,
        float* __restrict__ CTA, float* __restrict__ CTB) {
    const int b = blockIdx.y, c = blockIdx.x, f = threadIdx.x;
    const size_t base = (size_t)b * NN;
    float sA = 0.f, sB = 0.f;
#pragma unroll 8
    for (int r = 0; r < CHL; ++r) {
        int t = c * CHL + r;
        int j = p1[base + t];
        float xv = xf[(base + j) * FEAT + f];
        sA += as[base + t] * xv;
        sB += bs[base + t] * xv;
    }
    CTA[((size_t)b * NCH + c) * FEAT + f] = sA;
    CTB[((size_t)b * NCH + c) * FEAT + f] = sB;
}

__global__ __launch_bounds__(64) void kscanB(
        const int* __restrict__ p1, const float* __restrict__ as,
        const float* __restrict__ bs, const float* __restrict__ xf,
        const float* __restrict__ CTA, const float* __restrict__ CTB,
        float* __restrict__ PA, float* __restrict__ PB) {
    const int b = blockIdx.y, c = blockIdx.x, f = threadIdx.x;
    const size_t base = (size_t)b * NN;
    float offA = 0.f, offB = 0.f;
    for (int cc = 0; cc < NCH; ++cc) {
        float av = CTA[((size_t)b * NCH + cc) * FEAT + f];
        float bv = CTB[((size_t)b * NCH + cc) * FEAT + f];
        if (cc > c) offA += av;
        if (cc < c) offB += bv;
    }
    float run = offB;
#pragma unroll 4
    for (int r = 0; r < CHL; ++r) {
        int t = c * CHL + r;
        int j = p1[base + t];
        float xv = xf[(base + j) * FEAT + f];
        run += bs[base + t] * xv;
        PB[(base + t) * FEAT + f] = run;
    }
    run = offA;
#pragma unroll 4
    for (int r = CHL - 1; r >= 0; --r) {
        int t = c * CHL + r;
        int j = p1[base + t];
        float xv = xf[(base + j) * FEAT + f];
        run += as[base + t] * xv;
        PA[(base + t) * FEAT + f] = run;
    }
}

// ---------------------------------------------------------------- k4
__global__ __launch_bounds__(256) void k4_sep(
        const float* __restrict__ s2, const float* __restrict__ s1s,
        const float* __restrict__ PA, const float* __restrict__ PB,
        float* __restrict__ out) {
    const int b = blockIdx.y;
    const int i = blockIdx.x * 16 + (threadIdx.x >> 4);
    const int fg = threadIdx.x & 15;
    const size_t base = (size_t)b * NN;
    float s2v = s2[base + i];
    float thr = -s2v;
    const float* S1 = s1s + base;
    int lo = 0, hi = NN;
    while (lo < hi) { int mid = (lo + hi) >> 1; if (S1[mid] < thr) lo = mid + 1; else hi = mid; }
    float eA = __expf(s2v), eB = __expf(0.2f * s2v);
    float4 pa = make_float4(0.f, 0.f, 0.f, 0.f);
    float4 pb = make_float4(0.f, 0.f, 0.f, 0.f);
    if (lo < NN) pa = *(const float4*)(PA + (base + lo) * FEAT + fg * 4);
    if (lo > 0)  pb = *(const float4*)(PB + (base + lo - 1) * FEAT + fg * 4);
    float4 o;
    o.x = eA * pa.x + eB * pb.x;
    o.y = eA * pa.y + eB * pb.y;
    o.z = eA * pa.z + eB * pb.z;
    o.w = eA * pa.w + eB * pb.w;
    *(float4*)(out + (base + i) * FEAT + fg * 4) = o;
}

extern "C" void kernel_launch(void* const* d_in, const int* in_sizes, int n_in,
                              void* d_out, int out_size, void* d_ws, size_t ws_size,
                              hipStream_t stream) {
    const float* x      = (const float*)d_in[0];
    const float* n      = (const float*)d_in[1];
    const float* conv_w = (const float*)d_in[2];
    const float* conv_b = (const float*)d_in[3];
    const float* att1   = (const float*)d_in[4];
    const float* att2   = (const float*)d_in[5];
    float* outp = (float*)d_out;
    float* xf = outp;   // xf aliases d_out (k4_sep overwrites all of it)

    // ---- ws layout: smalls | xh(1040 rows) | xl(1040 rows) | PA | PB
    //      (Wh/Wl overlay PA/PB; nth/ntl are xh/xl rows 1024..1039;
    //       rows 1040..1087 read as junk land in the following buffer.)
    float* ws    = (float*)d_ws;
    float* s1    = ws;
    float* s2    = s1    + (size_t)BB * NN;
    float* nt    = s2    + (size_t)BB * NN;
    float* s1s   = nt    + (size_t)BB * NN;
    int*   p1    = (int*)(s1s + (size_t)BB * NN);
    float* s2s   = (float*)p1 + (size_t)BB * NN;
    float* E1suf = s2s   + (size_t)BB * NN;
    float* E2    = E1suf + (size_t)BB * NN;
    float* as    = E2    + (size_t)BB * NN;
    float* bs    = as    + (size_t)BB * NN;
    float* CTA   = bs    + (size_t)BB * NN;
    float* CTB   = CTA   + (size_t)BB * NCH * FEAT;
    ushort* xh   = (ushort*)(CTB + (size_t)BB * NCH * FEAT);  // 1040 rows
    ushort* nth  = xh + (size_t)1024 * NN;
    ushort* xl   = xh + (size_t)1040 * NN;                    // 1040 rows
    ushort* ntl  = xl + (size_t)1024 * NN;
    float* PA    = (float*)(xl + (size_t)1040 * NN);          // 8 MB
    float* PB    = PA + (size_t)BB * NN * FEAT;               // 8 MB
    ushort* Wh   = (ushort*)PA;                               // overlay
    ushort* Wl   = Wh + (size_t)NN * NN;

    const size_t need_mfma =
        (size_t)((char*)(PB + (size_t)BB * NN * FEAT) - (char*)d_ws);
    const bool use_mfma = ws_size >= need_mfma;   // call-invariant -> graph-safe

    k0_ntilde<<<dim3(BB * NN / 256), dim3(256), 0, stream>>>(
        n, att2, nt, nth, ntl, use_mfma ? 1 : 0);
    if (use_mfma) {
        k_cvtW<<<dim3(NN * NN / 1024), dim3(256), 0, stream>>>(conv_w, Wh, Wl);
        k_cvtX<<<dim3(NN / 64, BB), dim3(256), 0, stream>>>(x, xh, xl);
        k1_mfma2<<<dim3(544), dim3(256), 0, stream>>>(Wh, Wl, xh, xl,
                                                      conv_b, att2, xf, s2);
    } else {
        k1_conv<<<dim3(NN / BM, BB), dim3(256), 0, stream>>>(x, conv_w, conv_b, xf);
        k2_s2<<<dim3(NN * BB / 256), dim3(256), 0, stream>>>(conv_w, nt, conv_b,
                                                             att2, s2);
    }
    k2b_s1<<<dim3(BB * NN / 256), dim3(256), 0, stream>>>(xf, att1, s1);
    ksort<<<dim3(2, BB), dim3(1024), 0, stream>>>(s1, s2, s1s, p1, s2s, E1suf, E2);
    k_ab<<<dim3(BB * NN / 256), dim3(256), 0, stream>>>(s1s, s2s, E1suf, E2, as, bs);
    kscanA<<<dim3(NCH, BB), dim3(64), 0, stream>>>(p1, as, bs, xf, CTA, CTB);
    kscanB<<<dim3(NCH, BB), dim3(64), 0, stream>>>(p1, as, bs, xf, CTA, CTB, PA, PB);
    k4_sep<<<dim3(NN / 16, BB), dim3(256), 0, stream>>>(s2, s1s, PA, PB, outp);
}